// Round 1
// baseline (1333.506 us; speedup 1.0000x reference)
//
#include <hip/hip_runtime.h>

typedef unsigned short u16;
using f32x4 = __attribute__((ext_vector_type(4))) float;
using s16x8 = __attribute__((ext_vector_type(8))) short;

// ---- helpers ---------------------------------------------------------------
static __device__ __forceinline__ u16 f2b(float f) {
  unsigned int u = __builtin_bit_cast(unsigned int, f);
  u = (u + 0x7fffu + ((u >> 16) & 1u)) >> 16;   // RNE, finite inputs only
  return (u16)u;
}

// ---- GEMM: C[M,N] = A[M,K] * B[K,N], A fp32-or-bf16, B fp32, C fp32 --------
// 128x128 tile, 4 waves (2x2 of 64x64), BK=32, mfma_f32_16x16x32_bf16
template<bool ABF16>
__global__ __launch_bounds__(256) void gemm_kernel(
    const void* __restrict__ Aptr, const float* __restrict__ Bw,
    float* __restrict__ C, int M, int N, int K)
{
  __shared__ __align__(16) u16 aLds[128][40];   // [row][k], pad to 40 (80B rows, 16B-aligned)
  __shared__ __align__(16) u16 bLds[128][40];   // [col][k]  (B transposed)

  const int t    = threadIdx.x;
  const int lane = t & 63;
  const int w    = t >> 6;
  const int lr   = lane & 15;
  const int lg   = lane >> 4;
  const int wr   = w >> 1, wc = w & 1;
  const int m0   = blockIdx.y * 128, n0 = blockIdx.x * 128;

  f32x4 acc[4][4] = {};

  const int nk = K >> 5;
  for (int kt = 0; kt < nk; ++kt) {
    const int k0 = kt << 5;
    __syncthreads();
    // ---- stage A (convert to bf16 if needed) ----
    if constexpr (ABF16) {
      const u16* A = (const u16*)Aptr;
      #pragma unroll
      for (int i = 0; i < 2; ++i) {
        int idx = i * 256 + t;            // 0..511, 8 bf16 each
        int row = idx >> 2;
        int kc  = (idx & 3) << 3;
        uint4 v = *(const uint4*)(A + (size_t)(m0 + row) * K + k0 + kc);
        *(uint4*)&aLds[row][kc] = v;
      }
    } else {
      const float* A = (const float*)Aptr;
      #pragma unroll
      for (int i = 0; i < 4; ++i) {
        int idx = i * 256 + t;            // 0..1023, 4 floats each
        int row = idx >> 3;
        int kc  = (idx & 7) << 2;
        float4 v = *(const float4*)(A + (size_t)(m0 + row) * K + k0 + kc);
        ushort4 hh;
        hh.x = f2b(v.x); hh.y = f2b(v.y); hh.z = f2b(v.z); hh.w = f2b(v.w);
        *(ushort4*)&aLds[row][kc] = hh;
      }
    }
    // ---- stage B with transpose: bLds[n][k] = B[k0+k][n0+n] ----
    #pragma unroll
    for (int i = 0; i < 4; ++i) {
      int idx = i * 256 + t;              // 0..1023
      int kk  = idx >> 5;                 // 0..31
      int nc  = (idx & 31) << 2;          // 0..124
      int n   = n0 + nc;
      float4 v = make_float4(0.f, 0.f, 0.f, 0.f);
      if (n < N) v = *(const float4*)(Bw + (size_t)(k0 + kk) * N + n);
      bLds[nc + 0][kk] = f2b(v.x);
      bLds[nc + 1][kk] = f2b(v.y);
      bLds[nc + 2][kk] = f2b(v.z);
      bLds[nc + 3][kk] = f2b(v.w);
    }
    __syncthreads();
    // ---- fragments + MFMA ----
    s16x8 af[4], bf[4];
    #pragma unroll
    for (int m = 0; m < 4; ++m)
      af[m] = *(const s16x8*)&aLds[wr * 64 + m * 16 + lr][lg * 8];
    #pragma unroll
    for (int n = 0; n < 4; ++n)
      bf[n] = *(const s16x8*)&bLds[wc * 64 + n * 16 + lr][lg * 8];
    #pragma unroll
    for (int m = 0; m < 4; ++m)
      #pragma unroll
      for (int n = 0; n < 4; ++n)
        acc[m][n] = __builtin_amdgcn_mfma_f32_16x16x32_bf16(af[m], bf[n], acc[m][n], 0, 0, 0);
  }
  // ---- epilogue: fp32 store ----
  #pragma unroll
  for (int m = 0; m < 4; ++m) {
    int row = m0 + wr * 64 + m * 16 + lg * 4;
    #pragma unroll
    for (int n = 0; n < 4; ++n) {
      int col = n0 + wc * 64 + n * 16 + lr;
      if (col < N) {
        #pragma unroll
        for (int r = 0; r < 4; ++r)
          C[(size_t)(row + r) * N + col] = acc[m][n][r];
      }
    }
  }
}

// ---- RoPE + extract q/k/v from fused qkv -----------------------------------
// fused [2048][4672] fp32 -> q [B,71,S,64] bf16 (roped), k [B,S,64] bf16 (roped),
// vT [B,64,S] bf16
__global__ __launch_bounds__(256) void rope_extract(
    const float* __restrict__ fused, const int* __restrict__ pos_ids,
    u16* __restrict__ q, u16* __restrict__ kx, u16* __restrict__ vT)
{
  const int t   = threadIdx.x;
  const int row = blockIdx.x * 4 + (t >> 6);    // 0..2047
  const int d   = t & 63;
  const int b   = row >> 10, s = row & 1023;
  const float p = (float)pos_ids[s];
  // inv_freq = 10000^{-(d%32)/32} = exp2(-(d%32) * log2(10000)/32)
  const float inv = exp2f(-0.41524101186092029f * (float)(d & 31));
  float sn, cs;
  sincosf(p * inv, &sn, &cs);
  const float sgn = (d < 32) ? -1.f : 1.f;
  const int dp = (d + 32) & 63;
  const float* base = fused + (size_t)row * 4672;

  for (int h = 0; h < 71; ++h) {
    float x  = base[h * 64 + d];
    float xp = base[h * 64 + dp];
    q[((size_t)(b * 71 + h) * 1024 + s) * 64 + d] = f2b(x * cs + sgn * xp * sn);
  }
  {
    float x  = base[71 * 64 + d];
    float xp = base[71 * 64 + dp];
    kx[((size_t)b * 1024 + s) * 64 + d] = f2b(x * cs + sgn * xp * sn);
  }
  {
    float x = base[72 * 64 + d];
    vT[((size_t)b * 64 + d) * 1024 + s] = f2b(x);
  }
}

// ---- flash attention (causal, MQA) -----------------------------------------
// grid (S/64, NH, B), 4 waves; wave w owns rows q0 = qb*64 + w*16.
__global__ __launch_bounds__(256) void attn_kernel(
    const u16* __restrict__ q, const u16* __restrict__ kx,
    const u16* __restrict__ vT, u16* __restrict__ attnO)
{
  __shared__ __align__(16) u16 pLds[4][16][40];
  const int t = threadIdx.x, lane = t & 63, w = t >> 6;
  const int lr = lane & 15, lg = lane >> 4;
  const int qb = blockIdx.x, h = blockIdx.y, b = blockIdx.z;
  const int q0 = qb * 64 + w * 16;

  const u16* qbase = q + ((size_t)(b * 71 + h) * 1024 + q0 + lr) * 64 + lg * 8;
  const s16x8 aq0 = *(const s16x8*)qbase;
  const s16x8 aq1 = *(const s16x8*)(qbase + 32);

  f32x4 acc[4] = {};
  float mrow[4] = {-1e30f, -1e30f, -1e30f, -1e30f};
  float lrow[4] = {};

  const int kvEnd = qb * 64 + 64;          // block-uniform trip count
  for (int kv0 = 0; kv0 < kvEnd; kv0 += 32) {
    f32x4 st[2] = {};
    #pragma unroll
    for (int kt = 0; kt < 2; ++kt) {
      const u16* kb = kx + ((size_t)b * 1024 + kv0 + kt * 16 + lr) * 64 + lg * 8;
      s16x8 bk0 = *(const s16x8*)kb;
      s16x8 bk1 = *(const s16x8*)(kb + 32);
      st[kt] = __builtin_amdgcn_mfma_f32_16x16x32_bf16(aq0, bk0, st[kt], 0, 0, 0);
      st[kt] = __builtin_amdgcn_mfma_f32_16x16x32_bf16(aq1, bk1, st[kt], 0, 0, 0);
    }
    // mask + online softmax (4 rows per lane-group, one per reg r)
    #pragma unroll
    for (int r = 0; r < 4; ++r) {
      int row = q0 + lg * 4 + r;
      float s0 = st[0][r] * 0.125f;
      float s1 = st[1][r] * 0.125f;
      if (kv0 + lr > row)      s0 = -1e30f;
      if (kv0 + 16 + lr > row) s1 = -1e30f;
      float mx = fmaxf(s0, s1);
      #pragma unroll
      for (int off = 8; off; off >>= 1) mx = fmaxf(mx, __shfl_xor(mx, off));
      float mn   = fmaxf(mrow[r], mx);
      float corr = __expf(mrow[r] - mn);
      float p0 = __expf(s0 - mn);
      float p1 = __expf(s1 - mn);
      float ps = p0 + p1;
      #pragma unroll
      for (int off = 8; off; off >>= 1) ps += __shfl_xor(ps, off);
      lrow[r] = lrow[r] * corr + ps;
      mrow[r] = mn;
      #pragma unroll
      for (int t4 = 0; t4 < 4; ++t4) acc[t4][r] *= corr;
      pLds[w][lg * 4 + r][lr]      = f2b(p0);
      pLds[w][lg * 4 + r][16 + lr] = f2b(p1);
    }
    __syncthreads();
    // PV: A = P (from LDS), B = V^T rows (contiguous along keys)
    s16x8 pa = *(const s16x8*)&pLds[w][lr][lg * 8];
    #pragma unroll
    for (int t4 = 0; t4 < 4; ++t4) {
      const u16* vb = vT + ((size_t)b * 64 + t4 * 16 + lr) * 1024 + kv0 + lg * 8;
      s16x8 bv = *(const s16x8*)vb;
      acc[t4] = __builtin_amdgcn_mfma_f32_16x16x32_bf16(pa, bv, acc[t4], 0, 0, 0);
    }
    __syncthreads();
  }
  // epilogue: attn [B,S,NH,64] bf16
  #pragma unroll
  for (int t4 = 0; t4 < 4; ++t4) {
    #pragma unroll
    for (int r = 0; r < 4; ++r) {
      int row = q0 + lg * 4 + r;
      float o = acc[t4][r] / lrow[r];
      attnO[((size_t)(b * 1024 + row) * 71 + h) * 64 + t4 * 16 + lr] = f2b(o);
    }
  }
}

// ---- launcher --------------------------------------------------------------
extern "C" void kernel_launch(void* const* d_in, const int* in_sizes, int n_in,
                              void* d_out, int out_size, void* d_ws, size_t ws_size,
                              hipStream_t stream) {
  const float* hidden = (const float*)d_in[0];   // [2,1024,4544]
  const float* Wqkv   = (const float*)d_in[1];   // [4544,4672]
  const float* Wdense = (const float*)d_in[2];   // [4544,4544]
  const int*   pos    = (const int*)d_in[4];     // [1,1024]
  float* out = (float*)d_out;                    // [2,1024,4544] fp32

  char* wsp = (char*)d_ws;
  float* fused = (float*)wsp;                                    // 2048*4672*4 = 38273024
  u16* qws   = (u16*)(wsp + 38273024);                           // 18612224
  u16* kws   = (u16*)(wsp + 38273024 + 18612224);                // 262144
  u16* vws   = (u16*)(wsp + 38273024 + 18612224 + 262144);       // 262144
  u16* attnw = (u16*)(wsp + 38273024 + 18612224 + 2 * 262144);   // 18612224

  // 1) fused qkv = hidden @ W_qkv   (M=2048, N=4672, K=4544)
  gemm_kernel<false><<<dim3(37, 16), 256, 0, stream>>>(hidden, Wqkv, fused, 2048, 4672, 4544);
  // 2) RoPE + split into q/k/vT (bf16)
  rope_extract<<<512, 256, 0, stream>>>(fused, pos, qws, kws, vws);
  // 3) causal flash attention, MQA
  attn_kernel<<<dim3(16, 71, 2), 256, 0, stream>>>(qws, kws, vws, attnw);
  // 4) out = attn @ W_dense        (M=2048, N=4544, K=4544)
  gemm_kernel<true><<<dim3(36, 16), 256, 0, stream>>>(attnw, Wdense, out, 2048, 4544, 4544);
}

// Round 2
// 650.578 us; speedup vs baseline: 2.0497x; 2.0497x over previous
//
#include <hip/hip_runtime.h>

typedef unsigned short u16;
using f32x4 = __attribute__((ext_vector_type(4))) float;
using s16x8 = __attribute__((ext_vector_type(8))) short;

// ---- helpers ---------------------------------------------------------------
static __device__ __forceinline__ u16 f2b(float f) {
  unsigned int u = __builtin_bit_cast(unsigned int, f);
  u = (u + 0x7fffu + ((u >> 16) & 1u)) >> 16;   // RNE, finite inputs only
  return (u16)u;
}
static __device__ __forceinline__ float b2f(u16 h) {
  unsigned int u = ((unsigned int)h) << 16;
  return __builtin_bit_cast(float, u);
}
static __device__ __forceinline__ void gload16(const void* g, void* l) {
  __builtin_amdgcn_global_load_lds(
      (const __attribute__((address_space(1))) void*)g,
      (__attribute__((address_space(3))) void*)l, 16, 0, 0);
}

// ---- fp32 -> bf16 elementwise (8/thread) -----------------------------------
__global__ __launch_bounds__(256) void conv_bf16(
    const float* __restrict__ in, u16* __restrict__ out, int n8)
{
  int i = blockIdx.x * 256 + threadIdx.x;
  if (i >= n8) return;
  float4 a = *(const float4*)(in + (size_t)i * 8);
  float4 b = *(const float4*)(in + (size_t)i * 8 + 4);
  __align__(16) u16 tmp[8] = {f2b(a.x), f2b(a.y), f2b(a.z), f2b(a.w),
                              f2b(b.x), f2b(b.y), f2b(b.z), f2b(b.w)};
  *(uint4*)(out + (size_t)i * 8) = *(const uint4*)tmp;
}

// ---- W[K][N] fp32 -> Wt[Npad][K] bf16 (transpose+convert, zero pad) --------
// K%64==0, N%64==0, Npad%64==0. 64x64 tiles.
__global__ __launch_bounds__(256) void transpose_conv(
    const float* __restrict__ W, u16* __restrict__ Wt, int K, int N)
{
  __shared__ u16 tile[64][72];
  const int t = threadIdx.x;
  const int n0 = blockIdx.x * 64, k0 = blockIdx.y * 64;
  #pragma unroll
  for (int i = 0; i < 4; ++i) {
    int idx = i * 256 + t;
    int r = idx >> 4;            // k within tile
    int c = (idx & 15) << 2;     // n within tile
    float4 v = make_float4(0.f, 0.f, 0.f, 0.f);
    if (n0 + c < N) v = *(const float4*)(W + (size_t)(k0 + r) * N + n0 + c);
    tile[r][c + 0] = f2b(v.x);
    tile[r][c + 1] = f2b(v.y);
    tile[r][c + 2] = f2b(v.z);
    tile[r][c + 3] = f2b(v.w);
  }
  __syncthreads();
  #pragma unroll
  for (int i = 0; i < 2; ++i) {
    int idx = i * 256 + t;
    int rn = idx >> 3;           // n within tile
    int c8 = (idx & 7) << 3;     // k chunk
    __align__(16) u16 tmp[8];
    #pragma unroll
    for (int j = 0; j < 8; ++j) tmp[j] = tile[c8 + j][rn];
    *(uint4*)(Wt + (size_t)(n0 + rn) * K + k0 + c8) = *(const uint4*)tmp;
  }
}

// ---- GEMM: C[M,N] = A[M,K] * B^T  (A bf16 [M][K], B bf16 [Npad][K]) --------
// m97 structure: 128x128 tile, 4 waves (2x2 of 64x64), BK=32, global_load_lds.
template<bool OUT_BF16>
__global__ __launch_bounds__(256) void gemm_bt(
    const u16* __restrict__ A, const u16* __restrict__ B,
    void* __restrict__ Cptr, int M, int N, int K)
{
  __shared__ __align__(16) u16 aLds[128 * 32];
  __shared__ __align__(16) u16 bLds[128 * 32];

  const int t = threadIdx.x, lane = t & 63, w = t >> 6;
  const int lr = lane & 15, lg = lane >> 4;
  const int wr = w >> 1, wc = w & 1;
  const int m0 = blockIdx.y * 128, n0 = blockIdx.x * 128;

  const int srow = lane >> 2;            // 0..15
  const int skc  = (lane & 3) << 3;      // 0,8,16,24 (u16 units)

  f32x4 acc[4][4] = {};

  const int nk = K >> 5;
  for (int kt = 0; kt < nk; ++kt) {
    const int k0 = kt << 5;
    __syncthreads();
    #pragma unroll
    for (int i = 0; i < 2; ++i) {
      int row = i * 64 + w * 16 + srow;
      gload16(A + (size_t)(m0 + row) * K + k0 + skc,
              (char*)aLds + i * 4096 + w * 1024);
      gload16(B + (size_t)(n0 + row) * K + k0 + skc,
              (char*)bLds + i * 4096 + w * 1024);
    }
    __syncthreads();
    s16x8 af[4], bf[4];
    #pragma unroll
    for (int m = 0; m < 4; ++m)
      af[m] = *(const s16x8*)(aLds + (wr * 64 + m * 16 + lr) * 32 + lg * 8);
    #pragma unroll
    for (int n = 0; n < 4; ++n)
      bf[n] = *(const s16x8*)(bLds + (wc * 64 + n * 16 + lr) * 32 + lg * 8);
    #pragma unroll
    for (int m = 0; m < 4; ++m)
      #pragma unroll
      for (int n = 0; n < 4; ++n)
        acc[m][n] = __builtin_amdgcn_mfma_f32_16x16x32_bf16(af[m], bf[n], acc[m][n], 0, 0, 0);
  }

  #pragma unroll
  for (int m = 0; m < 4; ++m) {
    int row = m0 + wr * 64 + m * 16 + lg * 4;
    #pragma unroll
    for (int n = 0; n < 4; ++n) {
      int col = n0 + wc * 64 + n * 16 + lr;
      if (col < N) {
        #pragma unroll
        for (int r = 0; r < 4; ++r) {
          if constexpr (OUT_BF16)
            ((u16*)Cptr)[(size_t)(row + r) * N + col] = f2b(acc[m][n][r]);
          else
            ((float*)Cptr)[(size_t)(row + r) * N + col] = acc[m][n][r];
        }
      }
    }
  }
}

// ---- RoPE + extract q/k/v from fused qkv (bf16 in) -------------------------
__global__ __launch_bounds__(256) void rope_extract(
    const u16* __restrict__ fused, const int* __restrict__ pos_ids,
    u16* __restrict__ q, u16* __restrict__ kx, u16* __restrict__ vT)
{
  const int t   = threadIdx.x;
  const int row = blockIdx.x * 4 + (t >> 6);    // 0..2047
  const int d   = t & 63;
  const int b   = row >> 10, s = row & 1023;
  const float p = (float)pos_ids[s];
  const float inv = exp2f(-0.41524101186092029f * (float)(d & 31));
  float sn, cs;
  sincosf(p * inv, &sn, &cs);
  const float sgn = (d < 32) ? -1.f : 1.f;
  const int dp = (d + 32) & 63;
  const u16* base = fused + (size_t)row * 4672;

  for (int h = 0; h < 71; ++h) {
    float x  = b2f(base[h * 64 + d]);
    float xp = b2f(base[h * 64 + dp]);
    q[((size_t)(b * 71 + h) * 1024 + s) * 64 + d] = f2b(x * cs + sgn * xp * sn);
  }
  {
    float x  = b2f(base[71 * 64 + d]);
    float xp = b2f(base[71 * 64 + dp]);
    kx[((size_t)b * 1024 + s) * 64 + d] = f2b(x * cs + sgn * xp * sn);
  }
  vT[((size_t)b * 64 + d) * 1024 + s] = base[72 * 64 + d];
}

// ---- flash attention (causal, MQA) -----------------------------------------
__global__ __launch_bounds__(256) void attn_kernel(
    const u16* __restrict__ q, const u16* __restrict__ kx,
    const u16* __restrict__ vT, u16* __restrict__ attnO)
{
  __shared__ __align__(16) u16 pLds[4][16][40];
  const int t = threadIdx.x, lane = t & 63, w = t >> 6;
  const int lr = lane & 15, lg = lane >> 4;
  const int qb = blockIdx.x, h = blockIdx.y, b = blockIdx.z;
  const int q0 = qb * 64 + w * 16;

  const u16* qbase = q + ((size_t)(b * 71 + h) * 1024 + q0 + lr) * 64 + lg * 8;
  const s16x8 aq0 = *(const s16x8*)qbase;
  const s16x8 aq1 = *(const s16x8*)(qbase + 32);

  f32x4 acc[4] = {};
  float mrow[4] = {-1e30f, -1e30f, -1e30f, -1e30f};
  float lrow[4] = {};

  const int kvEnd = qb * 64 + 64;
  for (int kv0 = 0; kv0 < kvEnd; kv0 += 32) {
    f32x4 st[2] = {};
    #pragma unroll
    for (int kt = 0; kt < 2; ++kt) {
      const u16* kb = kx + ((size_t)b * 1024 + kv0 + kt * 16 + lr) * 64 + lg * 8;
      s16x8 bk0 = *(const s16x8*)kb;
      s16x8 bk1 = *(const s16x8*)(kb + 32);
      st[kt] = __builtin_amdgcn_mfma_f32_16x16x32_bf16(aq0, bk0, st[kt], 0, 0, 0);
      st[kt] = __builtin_amdgcn_mfma_f32_16x16x32_bf16(aq1, bk1, st[kt], 0, 0, 0);
    }
    #pragma unroll
    for (int r = 0; r < 4; ++r) {
      int row = q0 + lg * 4 + r;
      float s0 = st[0][r] * 0.125f;
      float s1 = st[1][r] * 0.125f;
      if (kv0 + lr > row)      s0 = -1e30f;
      if (kv0 + 16 + lr > row) s1 = -1e30f;
      float mx = fmaxf(s0, s1);
      #pragma unroll
      for (int off = 8; off; off >>= 1) mx = fmaxf(mx, __shfl_xor(mx, off));
      float mn   = fmaxf(mrow[r], mx);
      float corr = __expf(mrow[r] - mn);
      float p0 = __expf(s0 - mn);
      float p1 = __expf(s1 - mn);
      float ps = p0 + p1;
      #pragma unroll
      for (int off = 8; off; off >>= 1) ps += __shfl_xor(ps, off);
      lrow[r] = lrow[r] * corr + ps;
      mrow[r] = mn;
      #pragma unroll
      for (int t4 = 0; t4 < 4; ++t4) acc[t4][r] *= corr;
      pLds[w][lg * 4 + r][lr]      = f2b(p0);
      pLds[w][lg * 4 + r][16 + lr] = f2b(p1);
    }
    __syncthreads();
    s16x8 pa = *(const s16x8*)&pLds[w][lr][lg * 8];
    #pragma unroll
    for (int t4 = 0; t4 < 4; ++t4) {
      const u16* vb = vT + ((size_t)b * 64 + t4 * 16 + lr) * 1024 + kv0 + lg * 8;
      s16x8 bv = *(const s16x8*)vb;
      acc[t4] = __builtin_amdgcn_mfma_f32_16x16x32_bf16(pa, bv, acc[t4], 0, 0, 0);
    }
    __syncthreads();
  }
  #pragma unroll
  for (int t4 = 0; t4 < 4; ++t4) {
    #pragma unroll
    for (int r = 0; r < 4; ++r) {
      int row = q0 + lg * 4 + r;
      float o = acc[t4][r] / lrow[r];
      attnO[((size_t)(b * 1024 + row) * 71 + h) * 64 + t4 * 16 + lr] = f2b(o);
    }
  }
}

// ---- launcher --------------------------------------------------------------
extern "C" void kernel_launch(void* const* d_in, const int* in_sizes, int n_in,
                              void* d_out, int out_size, void* d_ws, size_t ws_size,
                              hipStream_t stream) {
  const float* hidden = (const float*)d_in[0];   // [2,1024,4544]
  const float* Wqkv   = (const float*)d_in[1];   // [4544,4672]
  const float* Wdense = (const float*)d_in[2];   // [4544,4544]
  const int*   pos    = (const int*)d_in[4];     // [1,1024]
  float* out = (float*)d_out;                    // [2,1024,4544] fp32

  char* wsp = (char*)d_ws;
  // buffer plan (lifetimes overlapped):
  //  buf0: Wt shared by both GEMMs          43,040,768 B  (4736x4544 bf16)
  //  buf1: A1 (hidden bf16) -> later q      18,612,224 B
  //  buf2: fused bf16 -> later attn output  19,136,512 B
  //  buf3: k bf16                              262,144 B
  //  buf4: vT bf16                             262,144 B
  u16* Wt    = (u16*)(wsp);
  u16* A1    = (u16*)(wsp + 43040768);
  u16* fused = (u16*)(wsp + 43040768 + 18612224);
  u16* kws   = (u16*)(wsp + 43040768 + 18612224 + 19136512);
  u16* vws   = (u16*)(wsp + 43040768 + 18612224 + 19136512 + 262144);
  u16* qws   = A1;        // reuse after GEMM1 consumes A1
  u16* attnw = fused;     // reuse after rope consumes fused

  // 1) hidden -> bf16
  conv_bf16<<<4544, 256, 0, stream>>>(hidden, A1, 2048 * 4544 / 8);
  // 2) W_qkv^T -> bf16 [4736][4544] (zero-padded)
  transpose_conv<<<dim3(74, 71), 256, 0, stream>>>(Wqkv, Wt, 4544, 4672);
  // 3) fused = A1 @ Wqkv  (M=2048, N=4672, K=4544), bf16 out
  gemm_bt<true><<<dim3(37, 16), 256, 0, stream>>>(A1, Wt, fused, 2048, 4672, 4544);
  // 4) RoPE + split
  rope_extract<<<512, 256, 0, stream>>>(fused, pos, qws, kws, vws);
  // 5) W_dense^T -> bf16 [4608][4544] (reuses Wt buffer)
  transpose_conv<<<dim3(72, 71), 256, 0, stream>>>(Wdense, Wt, 4544, 4544);
  // 6) attention
  attn_kernel<<<dim3(16, 71, 2), 256, 0, stream>>>(qws, kws, vws, attnw);
  // 7) out = attn @ W_dense (M=2048, N=4544, K=4544), fp32 out
  gemm_bt<false><<<dim3(36, 16), 256, 0, stream>>>(attnw, Wt, out, 2048, 4544, 4544);
}

// Round 3
// 462.142 us; speedup vs baseline: 2.8855x; 1.4077x over previous
//
#include <hip/hip_runtime.h>

typedef unsigned short u16;
using f32x4  = __attribute__((ext_vector_type(4))) float;
using f32x16 = __attribute__((ext_vector_type(16))) float;
using s16x8  = __attribute__((ext_vector_type(8))) short;

// ---- helpers ---------------------------------------------------------------
static __device__ __forceinline__ u16 f2b(float f) {
  unsigned int u = __builtin_bit_cast(unsigned int, f);
  u = (u + 0x7fffu + ((u >> 16) & 1u)) >> 16;   // RNE, finite inputs only
  return (u16)u;
}
static __device__ __forceinline__ float b2f(u16 h) {
  unsigned int u = ((unsigned int)h) << 16;
  return __builtin_bit_cast(float, u);
}
static __device__ __forceinline__ unsigned int cvtpk(float lo, float hi) {
  unsigned int r;
  asm("v_cvt_pk_bf16_f32 %0, %1, %2" : "=v"(r) : "v"(lo), "v"(hi));
  return r;
}
static __device__ __forceinline__ void gload16(const void* g, void* l) {
  __builtin_amdgcn_global_load_lds(
      (const __attribute__((address_space(1))) void*)g,
      (__attribute__((address_space(3))) void*)l, 16, 0, 0);
}

// ---- fp32 -> bf16 elementwise (8/thread) -----------------------------------
__global__ __launch_bounds__(256) void conv_bf16(
    const float* __restrict__ in, u16* __restrict__ out, int n8)
{
  int i = blockIdx.x * 256 + threadIdx.x;
  if (i >= n8) return;
  float4 a = *(const float4*)(in + (size_t)i * 8);
  float4 b = *(const float4*)(in + (size_t)i * 8 + 4);
  __align__(16) u16 tmp[8] = {f2b(a.x), f2b(a.y), f2b(a.z), f2b(a.w),
                              f2b(b.x), f2b(b.y), f2b(b.z), f2b(b.w)};
  *(uint4*)(out + (size_t)i * 8) = *(const uint4*)tmp;
}

// ---- W[K][N] fp32 -> Wt[Npad][K] bf16 (transpose+convert, zero pad) --------
__global__ __launch_bounds__(256) void transpose_conv(
    const float* __restrict__ W, u16* __restrict__ Wt, int K, int N)
{
  __shared__ u16 tile[64][72];
  const int t = threadIdx.x;
  const int n0 = blockIdx.x * 64, k0 = blockIdx.y * 64;
  #pragma unroll
  for (int i = 0; i < 4; ++i) {
    int idx = i * 256 + t;
    int r = idx >> 4;
    int c = (idx & 15) << 2;
    float4 v = make_float4(0.f, 0.f, 0.f, 0.f);
    if (n0 + c < N) v = *(const float4*)(W + (size_t)(k0 + r) * N + n0 + c);
    tile[r][c + 0] = f2b(v.x);
    tile[r][c + 1] = f2b(v.y);
    tile[r][c + 2] = f2b(v.z);
    tile[r][c + 3] = f2b(v.w);
  }
  __syncthreads();
  #pragma unroll
  for (int i = 0; i < 2; ++i) {
    int idx = i * 256 + t;
    int rn = idx >> 3;
    int c8 = (idx & 7) << 3;
    __align__(16) u16 tmp[8];
    #pragma unroll
    for (int j = 0; j < 8; ++j) tmp[j] = tile[c8 + j][rn];
    *(uint4*)(Wt + (size_t)(n0 + rn) * K + k0 + c8) = *(const uint4*)tmp;
  }
}

// ---- GEMM: C[M,N] = A[M,K] * B^T  (A bf16 [M][K], B bf16 [Npad][K]) --------
template<bool OUT_BF16>
__global__ __launch_bounds__(256) void gemm_bt(
    const u16* __restrict__ A, const u16* __restrict__ B,
    void* __restrict__ Cptr, int M, int N, int K)
{
  __shared__ __align__(16) u16 aLds[128 * 32];
  __shared__ __align__(16) u16 bLds[128 * 32];

  const int t = threadIdx.x, lane = t & 63, w = t >> 6;
  const int lr = lane & 15, lg = lane >> 4;
  const int wr = w >> 1, wc = w & 1;
  const int m0 = blockIdx.y * 128, n0 = blockIdx.x * 128;

  const int srow = lane >> 2;
  const int skc  = (lane & 3) << 3;

  f32x4 acc[4][4] = {};

  const int nk = K >> 5;
  for (int kt = 0; kt < nk; ++kt) {
    const int k0 = kt << 5;
    __syncthreads();
    #pragma unroll
    for (int i = 0; i < 2; ++i) {
      int row = i * 64 + w * 16 + srow;
      gload16(A + (size_t)(m0 + row) * K + k0 + skc,
              (char*)aLds + i * 4096 + w * 1024);
      gload16(B + (size_t)(n0 + row) * K + k0 + skc,
              (char*)bLds + i * 4096 + w * 1024);
    }
    __syncthreads();
    s16x8 af[4], bf[4];
    #pragma unroll
    for (int m = 0; m < 4; ++m)
      af[m] = *(const s16x8*)(aLds + (wr * 64 + m * 16 + lr) * 32 + lg * 8);
    #pragma unroll
    for (int n = 0; n < 4; ++n)
      bf[n] = *(const s16x8*)(bLds + (wc * 64 + n * 16 + lr) * 32 + lg * 8);
    #pragma unroll
    for (int m = 0; m < 4; ++m)
      #pragma unroll
      for (int n = 0; n < 4; ++n)
        acc[m][n] = __builtin_amdgcn_mfma_f32_16x16x32_bf16(af[m], bf[n], acc[m][n], 0, 0, 0);
  }

  #pragma unroll
  for (int m = 0; m < 4; ++m) {
    int row = m0 + wr * 64 + m * 16 + lg * 4;
    #pragma unroll
    for (int n = 0; n < 4; ++n) {
      int col = n0 + wc * 64 + n * 16 + lr;
      if (col < N) {
        #pragma unroll
        for (int r = 0; r < 4; ++r) {
          if constexpr (OUT_BF16)
            ((u16*)Cptr)[(size_t)(row + r) * N + col] = f2b(acc[m][n][r]);
          else
            ((float*)Cptr)[(size_t)(row + r) * N + col] = acc[m][n][r];
        }
      }
    }
  }
}

// ---- RoPE + extract q/k/v from fused qkv (bf16 in) -------------------------
__global__ __launch_bounds__(256) void rope_extract(
    const u16* __restrict__ fused, const int* __restrict__ pos_ids,
    u16* __restrict__ q, u16* __restrict__ kx, u16* __restrict__ vT)
{
  const int t   = threadIdx.x;
  const int row = blockIdx.x * 4 + (t >> 6);
  const int d   = t & 63;
  const int b   = row >> 10, s = row & 1023;
  const float p = (float)pos_ids[s];
  const float inv = exp2f(-0.41524101186092029f * (float)(d & 31));
  float sn, cs;
  sincosf(p * inv, &sn, &cs);
  const float sgn = (d < 32) ? -1.f : 1.f;
  const int dp = (d + 32) & 63;
  const u16* base = fused + (size_t)row * 4672;

  for (int h = 0; h < 71; ++h) {
    float x  = b2f(base[h * 64 + d]);
    float xp = b2f(base[h * 64 + dp]);
    q[((size_t)(b * 71 + h) * 1024 + s) * 64 + d] = f2b(x * cs + sgn * xp * sn);
  }
  {
    float x  = b2f(base[71 * 64 + d]);
    float xp = b2f(base[71 * 64 + dp]);
    kx[((size_t)b * 1024 + s) * 64 + d] = f2b(x * cs + sgn * xp * sn);
  }
  vT[((size_t)b * 64 + d) * 1024 + s] = base[72 * 64 + d];
}

// ---- flash attention (causal, MQA): swapped-QK 32x32 MFMA, in-reg softmax --
// Block = 128 threads = 2 waves. Wave w handles q-tile qt = w ? 31-pair : pair
// (32 q-rows). No LDS, no barriers. KVBLK=32.
__global__ __launch_bounds__(128) void attn_kernel(
    const u16* __restrict__ q, const u16* __restrict__ kx,
    const u16* __restrict__ vT, u16* __restrict__ attnO)
{
  const int t = threadIdx.x, lane = t & 63, w = t >> 6;
  const int lq  = lane & 31;          // q-col (QK) / d-col (PV)
  const int hi  = lane >> 5;
  const int hi4 = hi << 2;
  const int pair = blockIdx.x, h = blockIdx.y, b = blockIdx.z;
  const int qt = w ? (31 - pair) : pair;
  const int q0 = qt * 32;

  // Q fragment (B-operand): Q[q0+lq][8*hi + 16*kt + j]
  const u16* qbase = q + ((size_t)(b * 71 + h) * 1024 + q0 + lq) * 64 + hi * 8;
  s16x8 qf[4];
  #pragma unroll
  for (int kt = 0; kt < 4; ++kt) qf[kt] = *(const s16x8*)(qbase + kt * 16);

  f32x16 o0 = {}, o1 = {};
  float m = -1e30f, l = 0.f;

  const u16* kbase  = kx + ((size_t)b * 1024 + lq) * 64 + hi * 8;
  const u16* vbase0 = vT + ((size_t)b * 64 + lq) * 1024 + hi * 8;
  const u16* vbase1 = vbase0 + 32 * 1024;

  for (int it = 0; it <= qt; ++it) {
    const int kv0 = it * 32;
    // K fragments (A-operand): K[kv0+lq][8*hi + 16*kt + j]
    s16x8 kf[4];
    #pragma unroll
    for (int kt = 0; kt < 4; ++kt)
      kf[kt] = *(const s16x8*)(kbase + (size_t)kv0 * 64 + kt * 16);
    // V fragments (B-operand), issued early to fly under QK+softmax
    s16x8 v00 = *(const s16x8*)(vbase0 + kv0);
    s16x8 v01 = *(const s16x8*)(vbase0 + kv0 + 16);
    s16x8 v10 = *(const s16x8*)(vbase1 + kv0);
    s16x8 v11 = *(const s16x8*)(vbase1 + kv0 + 16);

    // S^T = K * Q^T : D[key=R(r,hi)][q=lq]; split acc to halve dep chain
    f32x16 sa = {}, sb = {};
    sa = __builtin_amdgcn_mfma_f32_32x32x16_bf16(kf[0], qf[0], sa, 0, 0, 0);
    sb = __builtin_amdgcn_mfma_f32_32x32x16_bf16(kf[1], qf[1], sb, 0, 0, 0);
    sa = __builtin_amdgcn_mfma_f32_32x32x16_bf16(kf[2], qf[2], sa, 0, 0, 0);
    sb = __builtin_amdgcn_mfma_f32_32x32x16_bf16(kf[3], qf[3], sb, 0, 0, 0);

    float s[16];
    float pmax = -1e30f;
    if (it == qt) {                    // diagonal tile: causal mask
      #pragma unroll
      for (int r = 0; r < 16; ++r) {
        int R = (r & 3) + ((r >> 2) << 3) + hi4;
        s[r] = (R > lq) ? -1e30f : (sa[r] + sb[r]) * 0.125f;
        pmax = fmaxf(pmax, s[r]);
      }
    } else {
      #pragma unroll
      for (int r = 0; r < 16; ++r) {
        s[r] = (sa[r] + sb[r]) * 0.125f;
        pmax = fmaxf(pmax, s[r]);
      }
    }
    pmax = fmaxf(pmax, __shfl_xor(pmax, 32));   // full row max

    if (!__all(pmax <= m + 8.f)) {              // defer-max (T13)
      float mn = fmaxf(m, pmax);
      float corr = __expf(m - mn);
      m = mn;
      l *= corr;
      #pragma unroll
      for (int r = 0; r < 16; ++r) {
        float c2 = __shfl(corr, (r & 3) + ((r >> 2) << 3) + hi4);
        o0[r] *= c2; o1[r] *= c2;
      }
    }

    float p[16], sum = 0.f;
    #pragma unroll
    for (int r = 0; r < 16; ++r) { p[r] = __expf(s[r] - m); sum += p[r]; }
    sum += __shfl_xor(sum, 32);
    l += sum;

    // P -> PV A-fragment: cvt_pk pairs + permlane32_swap (T12)
    unsigned int a0 = cvtpk(p[0], p[1]),   a1 = cvtpk(p[2], p[3]);
    unsigned int b0 = cvtpk(p[4], p[5]),   b1 = cvtpk(p[6], p[7]);
    asm("v_permlane32_swap_b32 %0, %1" : "+v"(a0), "+v"(b0));
    asm("v_permlane32_swap_b32 %0, %1" : "+v"(a1), "+v"(b1));
    unsigned int c0 = cvtpk(p[8], p[9]),   c1 = cvtpk(p[10], p[11]);
    unsigned int d0 = cvtpk(p[12], p[13]), d1 = cvtpk(p[14], p[15]);
    asm("v_permlane32_swap_b32 %0, %1" : "+v"(c0), "+v"(d0));
    asm("v_permlane32_swap_b32 %0, %1" : "+v"(c1), "+v"(d1));
    union { unsigned int wd[4]; s16x8 v; } palo, pahi;
    palo.wd[0] = a0; palo.wd[1] = a1; palo.wd[2] = b0; palo.wd[3] = b1;
    pahi.wd[0] = c0; pahi.wd[1] = c1; pahi.wd[2] = d0; pahi.wd[3] = d1;

    // O[q=R][d=lq(+32)] += P * V
    o0 = __builtin_amdgcn_mfma_f32_32x32x16_bf16(palo.v, v00, o0, 0, 0, 0);
    o0 = __builtin_amdgcn_mfma_f32_32x32x16_bf16(pahi.v, v01, o0, 0, 0, 0);
    o1 = __builtin_amdgcn_mfma_f32_32x32x16_bf16(palo.v, v10, o1, 0, 0, 0);
    o1 = __builtin_amdgcn_mfma_f32_32x32x16_bf16(pahi.v, v11, o1, 0, 0, 0);
  }

  float linv = 1.f / l;
  #pragma unroll
  for (int r = 0; r < 16; ++r) {
    int R = (r & 3) + ((r >> 2) << 3) + hi4;
    float c2 = __shfl(linv, R);
    size_t base = ((size_t)(b * 1024 + q0 + R) * 71 + h) * 64;
    attnO[base + lq]      = f2b(o0[r] * c2);
    attnO[base + 32 + lq] = f2b(o1[r] * c2);
  }
}

// ---- launcher --------------------------------------------------------------
extern "C" void kernel_launch(void* const* d_in, const int* in_sizes, int n_in,
                              void* d_out, int out_size, void* d_ws, size_t ws_size,
                              hipStream_t stream) {
  const float* hidden = (const float*)d_in[0];   // [2,1024,4544]
  const float* Wqkv   = (const float*)d_in[1];   // [4544,4672]
  const float* Wdense = (const float*)d_in[2];   // [4544,4544]
  const int*   pos    = (const int*)d_in[4];     // [1,1024]
  float* out = (float*)d_out;                    // [2,1024,4544] fp32

  char* wsp = (char*)d_ws;
  u16* Wt    = (u16*)(wsp);
  u16* A1    = (u16*)(wsp + 43040768);
  u16* fused = (u16*)(wsp + 43040768 + 18612224);
  u16* kws   = (u16*)(wsp + 43040768 + 18612224 + 19136512);
  u16* vws   = (u16*)(wsp + 43040768 + 18612224 + 19136512 + 262144);
  u16* qws   = A1;        // reuse after GEMM1 consumes A1
  u16* attnw = fused;     // reuse after rope consumes fused

  // 1) hidden -> bf16
  conv_bf16<<<4544, 256, 0, stream>>>(hidden, A1, 2048 * 4544 / 8);
  // 2) W_qkv^T -> bf16 [4736][4544] (zero-padded)
  transpose_conv<<<dim3(74, 71), 256, 0, stream>>>(Wqkv, Wt, 4544, 4672);
  // 3) fused = A1 @ Wqkv  (M=2048, N=4672, K=4544), bf16 out
  gemm_bt<true><<<dim3(37, 16), 256, 0, stream>>>(A1, Wt, fused, 2048, 4672, 4544);
  // 4) RoPE + split
  rope_extract<<<512, 256, 0, stream>>>(fused, pos, qws, kws, vws);
  // 5) W_dense^T -> bf16 [4608][4544]
  transpose_conv<<<dim3(72, 71), 256, 0, stream>>>(Wdense, Wt, 4544, 4544);
  // 6) attention: 2 waves/block, balanced qt pairing
  attn_kernel<<<dim3(16, 71, 2), 128, 0, stream>>>(qws, kws, vws, attnw);
  // 7) out = attn @ W_dense (M=2048, N=4544, K=4544), fp32 out
  gemm_bt<false><<<dim3(36, 16), 256, 0, stream>>>(attnw, Wt, out, 2048, 4544, 4544);
}